// Round 1
// baseline (271.661 us; speedup 1.0000x reference)
//
#include <hip/hip_runtime.h>

#define Dc 256
#define Bc 4
#define Fc 60082
#define KNc 64
#define KHc 128

// workspace layout (floats):
//   [0,256)    u  = W_proj @ w_ff
//   [256,384)  v2 = W2 @ w_ff
//   [384,388)  constb[b] = company_out[b] + b_fc + b_ff
//   [388]      c2 = b2 . w_ff
//   [389]      c0 = b_proj . w_ff
//   [512,512+F) s[f] = field_table[f] . u + c0

__device__ __forceinline__ float wave_reduce_sum(float v) {
    #pragma unroll
    for (int off = 32; off > 0; off >>= 1)
        v += __shfl_down(v, off, 64);
    return v;
}

__global__ void k_pre(const float* __restrict__ company_emb,
                      const float* __restrict__ comp_table,
                      const float* __restrict__ W_proj,
                      const float* __restrict__ b_proj,
                      const float* __restrict__ theta,
                      const float* __restrict__ w_ff,
                      const float* __restrict__ b_ff,
                      const float* __restrict__ w_fc,
                      const float* __restrict__ b_fc,
                      const float* __restrict__ W2,
                      const float* __restrict__ b2,
                      const int* __restrict__ com_id,
                      float* __restrict__ ws)
{
    int t = threadIdx.x;
    float* u      = ws;
    float* v2     = ws + 256;
    float* constb = ws + 384;
    float* scal   = ws + 388;  // [c2, c0]

    // u[t] = W_proj[t,:] . w_ff
    {
        float acc = 0.f;
        const float* row = W_proj + t * Dc;
        #pragma unroll 4
        for (int i = 0; i < Dc; ++i) acc += row[i] * w_ff[i];
        u[t] = acc;
    }
    if (t < 128) {
        float acc = 0.f;
        const float* row = W2 + t * Dc;
        #pragma unroll 4
        for (int i = 0; i < Dc; ++i) acc += row[i] * w_ff[i];
        v2[t] = acc;
    }
    if (t == 0) {
        float c2 = 0.f, c0 = 0.f;
        for (int i = 0; i < Dc; ++i) { c2 += b2[i] * w_ff[i]; c0 += b_proj[i] * w_ff[i]; }
        scal[0] = c2;
        scal[1] = c0;
    }
    if (t < Bc) {
        int cid = com_id[t];
        float th = theta[cid];
        const float* ce = company_emb + t * Dc;
        const float* ct = comp_table + (size_t)cid * Dc;
        float acc = 0.f;
        for (int i = 0; i < Dc; ++i)
            acc += ((1.f - th) * ce[i] + th * ct[i]) * w_fc[i];
        constb[t] = acc + b_fc[0] + b_ff[0];
    }
}

// one wave per field row: s[f] = field_table[f,:] . u + c0
__global__ void k_s(const float* __restrict__ field_table,
                    const float* __restrict__ ws_u,
                    const float* __restrict__ ws_scal,
                    float* __restrict__ s)
{
    int w = (blockIdx.x * blockDim.x + threadIdx.x) >> 6;
    int lane = threadIdx.x & 63;
    if (w >= Fc) return;
    const float4* row = (const float4*)(field_table + (size_t)w * Dc);
    const float4* uu  = (const float4*)ws_u;
    float4 a = row[lane];
    float4 b = uu[lane];
    float acc = a.x*b.x + a.y*b.y + a.z*b.z + a.w*b.w;
    acc = wave_reduce_sum(acc);
    if (lane == 0) s[w] = acc + ws_scal[1];
}

// out[b*F+f] = s[f] + constb[b]
__global__ void k_bcast(const float* __restrict__ s,
                        const float* __restrict__ constb,
                        float* __restrict__ out)
{
    int i = blockIdx.x * blockDim.x + threadIdx.x;
    if (i >= Bc * Fc) return;
    int b = i / Fc;
    int f = i - b * Fc;
    out[i] = s[f] + constb[b];
}

// one wave per (b, node-slot): overwrite marked positions with full final value
__global__ void k_fix(const float* __restrict__ field_emb,
                      const float* __restrict__ raw_field_embed,
                      const float* __restrict__ alpha_fields,
                      const float* __restrict__ w_ff,
                      const float* __restrict__ W1,
                      const float* __restrict__ b1,
                      const float* __restrict__ ws,   // u/v2/constb/scal
                      const float* __restrict__ s,
                      const int* __restrict__ now_nodes,
                      const int* __restrict__ his_nodes,
                      float* __restrict__ out)
{
    const float* v2     = ws + 256;
    const float* constb = ws + 384;
    const float* scal   = ws + 388;

    const int NPB = KNc + KHc; // 192 node slots per b
    int gw = (blockIdx.x * blockDim.x + threadIdx.x) >> 6;
    int lane = threadIdx.x & 63;
    if (gw >= Bc * NPB) return;
    int b = gw / NPB;
    int k = gw - b * NPB;
    int f = (k < KNc) ? now_nodes[b * KNc + k]
                      : his_nodes[b * KHc + (k - KNc)];

    // membership tests (wave-cooperative scans)
    int nn = now_nodes[b * KNc + lane];
    bool in_now = __any(nn == f);
    int h0 = his_nodes[b * KHc + lane];
    int h1 = his_nodes[b * KHc + 64 + lane];
    bool in_his = __any((h0 == f) || (h1 == f));

    float alpha = alpha_fields[f];
    float val = (1.f - alpha) * s[f] + constb[b];

    if (in_now) {
        const float4* row = (const float4*)(field_emb + (size_t)f * Dc);
        const float4* w   = (const float4*)w_ff;
        float4 a = row[lane];
        float4 ww = w[lane];
        float acc = a.x*ww.x + a.y*ww.y + a.z*ww.z + a.w*ww.w;
        acc = wave_reduce_sum(acc);
        acc = __shfl(acc, 0, 64);
        val += alpha * acc;
    }
    if (in_his) {
        // g = leaky(raw_field_embed[f,:] @ W1 + b1);  hf = g . v2 + c2
        float acc0 = 0.f, acc1 = 0.f;
        const float* raw = raw_field_embed + (size_t)f * Dc;
        #pragma unroll 4
        for (int d = 0; d < Dc; ++d) {
            float r = raw[d];
            acc0 += r * W1[d * 128 + lane];
            acc1 += r * W1[d * 128 + 64 + lane];
        }
        float g0 = acc0 + b1[lane];
        float g1 = acc1 + b1[64 + lane];
        g0 = (g0 >= 0.f) ? g0 : 0.01f * g0;
        g1 = (g1 >= 0.f) ? g1 : 0.01f * g1;
        float p = g0 * v2[lane] + g1 * v2[64 + lane];
        p = wave_reduce_sum(p);
        p = __shfl(p, 0, 64);
        val += alpha * (p + scal[0]);
    }
    if (lane == 0) out[(size_t)b * Fc + f] = val;
}

extern "C" void kernel_launch(void* const* d_in, const int* in_sizes, int n_in,
                              void* d_out, int out_size, void* d_ws, size_t ws_size,
                              hipStream_t stream) {
    const float* company_emb     = (const float*)d_in[0];
    const float* field_emb       = (const float*)d_in[1];
    const float* raw_field_embed = (const float*)d_in[2];
    const float* comp_table      = (const float*)d_in[3];
    const float* field_table     = (const float*)d_in[4];
    const float* W_proj          = (const float*)d_in[5];
    const float* b_proj          = (const float*)d_in[6];
    const float* theta           = (const float*)d_in[7];
    const float* alpha_fields    = (const float*)d_in[8];
    const float* w_ff            = (const float*)d_in[9];
    const float* b_ff            = (const float*)d_in[10];
    const float* w_fc            = (const float*)d_in[11];
    const float* b_fc            = (const float*)d_in[12];
    const float* W1              = (const float*)d_in[13];
    const float* b1              = (const float*)d_in[14];
    const float* W2              = (const float*)d_in[15];
    const float* b2              = (const float*)d_in[16];
    const int*   now_nodes       = (const int*)d_in[17];
    const int*   his_nodes       = (const int*)d_in[18];
    const int*   com_id          = (const int*)d_in[19];

    float* ws = (float*)d_ws;
    float* s  = ws + 512;
    float* out = (float*)d_out;

    k_pre<<<1, 256, 0, stream>>>(company_emb, comp_table, W_proj, b_proj, theta,
                                 w_ff, b_ff, w_fc, b_fc, W2, b2, com_id, ws);

    int s_blocks = (Fc + 3) / 4;  // 4 waves (rows) per 256-thread block
    k_s<<<s_blocks, 256, 0, stream>>>(field_table, ws, ws + 388, s);

    int bc_blocks = (Bc * Fc + 255) / 256;
    k_bcast<<<bc_blocks, 256, 0, stream>>>(s, ws + 384, out);

    int fix_blocks = (Bc * (KNc + KHc)) / 4;  // one wave per node slot
    k_fix<<<fix_blocks, 256, 0, stream>>>(field_emb, raw_field_embed, alpha_fields,
                                          w_ff, W1, b1, ws, s,
                                          now_nodes, his_nodes, out);
}

// Round 2
// 230.590 us; speedup vs baseline: 1.1781x; 1.1781x over previous
//
#include <hip/hip_runtime.h>

#define Dc 256
#define Bc 4
#define Fc 60082
#define KNc 64
#define KHc 128

// workspace layout (floats):
//   [0,256)    u  = W_proj @ w_ff
//   [256,384)  v2 = W2 @ w_ff
//   [384,388)  constb[b] = company_out[b] + b_fc + b_ff
//   [388]      c2 = b2 . w_ff
//   [389]      c0 = b_proj . w_ff
//   [512,512+F) s[f] = field_table[f] . u + c0

__device__ __forceinline__ float wave_reduce_sum_bfly(float v) {
    #pragma unroll
    for (int off = 32; off > 0; off >>= 1)
        v += __shfl_xor(v, off, 64);
    return v;   // all lanes hold the sum
}

// 390 independent length-256 dot products, one wave each.
__global__ void k_pre(const float* __restrict__ company_emb,
                      const float* __restrict__ comp_table,
                      const float* __restrict__ W_proj,
                      const float* __restrict__ b_proj,
                      const float* __restrict__ theta,
                      const float* __restrict__ w_ff,
                      const float* __restrict__ b_ff,
                      const float* __restrict__ w_fc,
                      const float* __restrict__ b_fc,
                      const float* __restrict__ W2,
                      const float* __restrict__ b2,
                      const int* __restrict__ com_id,
                      float* __restrict__ ws)
{
    int gw = (blockIdx.x * blockDim.x + threadIdx.x) >> 6;
    int lane = threadIdx.x & 63;
    if (gw >= 390) return;

    const float4* wf4 = (const float4*)w_ff;
    float val = 0.f;
    float addend = 0.f;
    float* dst;

    if (gw < 256) {                       // u
        float4 a = ((const float4*)(W_proj + (size_t)gw * Dc))[lane];
        float4 b = wf4[lane];
        val = a.x*b.x + a.y*b.y + a.z*b.z + a.w*b.w;
        dst = ws + gw;
    } else if (gw < 384) {                // v2
        int j = gw - 256;
        float4 a = ((const float4*)(W2 + (size_t)j * Dc))[lane];
        float4 b = wf4[lane];
        val = a.x*b.x + a.y*b.y + a.z*b.z + a.w*b.w;
        dst = ws + 256 + j;
    } else if (gw < 388) {                // constb
        int b_ = gw - 384;
        int cid = com_id[b_];
        float th = theta[cid];
        float4 x = ((const float4*)(company_emb + (size_t)b_ * Dc))[lane];
        float4 y = ((const float4*)(comp_table + (size_t)cid * Dc))[lane];
        float4 w = ((const float4*)w_fc)[lane];
        float4 m;
        m.x = (1.f - th) * x.x + th * y.x;
        m.y = (1.f - th) * x.y + th * y.y;
        m.z = (1.f - th) * x.z + th * y.z;
        m.w = (1.f - th) * x.w + th * y.w;
        val = m.x*w.x + m.y*w.y + m.z*w.z + m.w*w.w;
        addend = b_fc[0] + b_ff[0];
        dst = ws + 384 + b_;
    } else if (gw == 388) {               // c2 = b2 . w_ff
        float4 a = ((const float4*)b2)[lane];
        float4 b = wf4[lane];
        val = a.x*b.x + a.y*b.y + a.z*b.z + a.w*b.w;
        dst = ws + 388;
    } else {                              // c0 = b_proj . w_ff
        float4 a = ((const float4*)b_proj)[lane];
        float4 b = wf4[lane];
        val = a.x*b.x + a.y*b.y + a.z*b.z + a.w*b.w;
        dst = ws + 389;
    }
    val = wave_reduce_sum_bfly(val);
    if (lane == 0) *dst = val + addend;
}

#define RPW 4
// one wave per 4 field rows: s[f] = field_table[f,:].u + c0, and fused
// broadcast write out[b*F+f] = s[f] + constb[b]
__global__ void k_s(const float* __restrict__ field_table,
                    const float* __restrict__ ws,
                    float* __restrict__ s,
                    float* __restrict__ out)
{
    int gw = (blockIdx.x * blockDim.x + threadIdx.x) >> 6;
    int lane = threadIdx.x & 63;
    int f0 = gw * RPW;
    if (f0 >= Fc) return;

    float4 b = ((const float4*)ws)[lane];
    float c0 = ws[389];

    float acc[RPW];
    #pragma unroll
    for (int r = 0; r < RPW; ++r) {
        int f = f0 + r;
        float4 a = make_float4(0.f, 0.f, 0.f, 0.f);
        if (f < Fc) a = ((const float4*)(field_table + (size_t)f * Dc))[lane];
        acc[r] = a.x*b.x + a.y*b.y + a.z*b.z + a.w*b.w;
    }
    #pragma unroll
    for (int r = 0; r < RPW; ++r)
        acc[r] = wave_reduce_sum_bfly(acc[r]);

    // all lanes hold all 4 sums; select by index with cndmask chain
    auto pick = [&](int i) {
        float v = acc[0];
        v = (i == 1) ? acc[1] : v;
        v = (i == 2) ? acc[2] : v;
        v = (i == 3) ? acc[3] : v;
        return v;
    };

    if (lane < 16) {            // out writes: lanes 0-3 -> b=0 f0..f0+3 (coalesced 16B runs)
        int r  = lane & 3;
        int bb = lane >> 2;
        int f  = f0 + r;
        if (f < Fc) out[(size_t)bb * Fc + f] = pick(r) + c0 + ws[384 + bb];
    } else if (lane >= 60) {    // s writes
        int r = lane - 60;
        int f = f0 + r;
        if (f < Fc) s[f] = pick(r) + c0;
    }
}

// one wave per (b, node-slot): overwrite marked positions with full final value
__global__ void k_fix(const float* __restrict__ field_emb,
                      const float* __restrict__ raw_field_embed,
                      const float* __restrict__ alpha_fields,
                      const float* __restrict__ w_ff,
                      const float* __restrict__ W1,
                      const float* __restrict__ b1,
                      const float* __restrict__ ws,   // u/v2/constb/scal
                      const float* __restrict__ s,
                      const int* __restrict__ now_nodes,
                      const int* __restrict__ his_nodes,
                      float* __restrict__ out)
{
    const float* v2     = ws + 256;
    const float* constb = ws + 384;
    const float* scal   = ws + 388;

    const int NPB = KNc + KHc; // 192 node slots per b
    int gw = (blockIdx.x * blockDim.x + threadIdx.x) >> 6;
    int lane = threadIdx.x & 63;
    if (gw >= Bc * NPB) return;
    int b = gw / NPB;
    int k = gw - b * NPB;
    int f = (k < KNc) ? now_nodes[b * KNc + k]
                      : his_nodes[b * KHc + (k - KNc)];

    // membership tests (wave-cooperative scans)
    int nn = now_nodes[b * KNc + lane];
    bool in_now = __any(nn == f);
    int h0 = his_nodes[b * KHc + lane];
    int h1 = his_nodes[b * KHc + 64 + lane];
    bool in_his = __any((h0 == f) || (h1 == f));

    float alpha = alpha_fields[f];
    float val = (1.f - alpha) * s[f] + constb[b];

    if (in_now) {
        float4 a  = ((const float4*)(field_emb + (size_t)f * Dc))[lane];
        float4 ww = ((const float4*)w_ff)[lane];
        float acc = a.x*ww.x + a.y*ww.y + a.z*ww.z + a.w*ww.w;
        acc = wave_reduce_sum_bfly(acc);
        val += alpha * acc;
    }
    if (in_his) {
        // g = leaky(raw_field_embed[f,:] @ W1 + b1);  hf = g . v2 + c2
        float acc0 = 0.f, acc1 = 0.f;
        const float4* raw4 = (const float4*)(raw_field_embed + (size_t)f * Dc);
        #pragma unroll 2
        for (int d4 = 0; d4 < Dc / 4; ++d4) {
            float4 r4 = raw4[d4];
            const float* base = W1 + d4 * 4 * 128;
            acc0 += r4.x * base[lane]       + r4.y * base[128 + lane]
                  + r4.z * base[256 + lane] + r4.w * base[384 + lane];
            acc1 += r4.x * base[64 + lane]      + r4.y * base[128 + 64 + lane]
                  + r4.z * base[256 + 64 + lane] + r4.w * base[384 + 64 + lane];
        }
        float g0 = acc0 + b1[lane];
        float g1 = acc1 + b1[64 + lane];
        g0 = (g0 >= 0.f) ? g0 : 0.01f * g0;
        g1 = (g1 >= 0.f) ? g1 : 0.01f * g1;
        float p = g0 * v2[lane] + g1 * v2[64 + lane];
        p = wave_reduce_sum_bfly(p);
        val += alpha * (p + scal[0]);
    }
    if (lane == 0) out[(size_t)b * Fc + f] = val;
}

extern "C" void kernel_launch(void* const* d_in, const int* in_sizes, int n_in,
                              void* d_out, int out_size, void* d_ws, size_t ws_size,
                              hipStream_t stream) {
    const float* company_emb     = (const float*)d_in[0];
    const float* field_emb       = (const float*)d_in[1];
    const float* raw_field_embed = (const float*)d_in[2];
    const float* comp_table      = (const float*)d_in[3];
    const float* field_table     = (const float*)d_in[4];
    const float* W_proj          = (const float*)d_in[5];
    const float* b_proj          = (const float*)d_in[6];
    const float* theta           = (const float*)d_in[7];
    const float* alpha_fields    = (const float*)d_in[8];
    const float* w_ff            = (const float*)d_in[9];
    const float* b_ff            = (const float*)d_in[10];
    const float* w_fc            = (const float*)d_in[11];
    const float* b_fc            = (const float*)d_in[12];
    const float* W1              = (const float*)d_in[13];
    const float* b1              = (const float*)d_in[14];
    const float* W2              = (const float*)d_in[15];
    const float* b2              = (const float*)d_in[16];
    const int*   now_nodes       = (const int*)d_in[17];
    const int*   his_nodes       = (const int*)d_in[18];
    const int*   com_id          = (const int*)d_in[19];

    float* ws  = (float*)d_ws;
    float* s   = ws + 512;
    float* out = (float*)d_out;

    // 390 waves -> 98 blocks of 4 waves
    k_pre<<<(390 + 3) / 4, 256, 0, stream>>>(company_emb, comp_table, W_proj, b_proj,
                                             theta, w_ff, b_ff, w_fc, b_fc, W2, b2,
                                             com_id, ws);

    // one wave per 4 rows
    int waves = (Fc + RPW - 1) / RPW;
    k_s<<<(waves + 3) / 4, 256, 0, stream>>>(field_table, ws, s, out);

    // one wave per node slot
    int fix_blocks = (Bc * (KNc + KHc)) / 4;
    k_fix<<<fix_blocks, 256, 0, stream>>>(field_emb, raw_field_embed, alpha_fields,
                                          w_ff, W1, b1, ws, s,
                                          now_nodes, his_nodes, out);
}